// Round 8
// baseline (15535.208 us; speedup 1.0000x reference)
//
#include <hip/hip_runtime.h>

#define T_LEN 16384
#define NT 1024
#define NBLK 64      // blocks per direction (x2 directions)
#define CPB 16       // columns (fwd) / rows (bwd) per block
#define NTHR 256     // 4 waves
#define MID 8191     // fwd computes alpha_MID (8191 steps); bwd beta_MID (8192 steps)

typedef unsigned long long u64;
typedef unsigned int u32;
typedef __attribute__((ext_vector_type(4))) u32 u32x4;

// Exchange buffers (proven protocol): [0..NT) even-parity tags, [NT..2NT) odd.
// tagged word = (step_tag << 32) | float_bits; tag+data fused => no fences needed.
__device__ __align__(32) u64 g_fbuf[2 * NT];
__device__ __align__(32) u64 g_bbuf[2 * NT];

__device__ __forceinline__ u64 pack_tag(u32 tag, float v) {
  return ((u64)tag << 32) | (u64)__float_as_uint(v);
}
__device__ __forceinline__ u64 ld_tag(const u64* p) {
  return __hip_atomic_load(p, __ATOMIC_RELAXED, __HIP_MEMORY_SCOPE_AGENT);
}
__device__ __forceinline__ void st_tag(u64* p, u64 v) {
  __hip_atomic_store(p, v, __ATOMIC_RELAXED, __HIP_MEMORY_SCOPE_AGENT);
}

// Issue 4 contiguous tagged words (32B) as 2 dwordx4 WITHOUT waiting.
// sc0+sc1 => coherent at MALL (same point as the agent-scope atomic path).
__device__ __forceinline__ void ld8_issue(const u64* q, u32x4& A, u32x4& B) {
  asm volatile("global_load_dwordx4 %0, %2, off sc0 sc1\n\t"
               "global_load_dwordx4 %1, %2, off offset:16 sc0 sc1"
               : "=&v"(A), "=&v"(B)
               : "v"(q)
               : "memory");
}
// Wait for ALL outstanding VMEM (the poll pair + any emit load), pinning the
// pair's registers; sched_barrier stops consumer hoisting (rule #18).
__device__ __forceinline__ void vm_wait0p(u32x4& A, u32x4& B) {
  asm volatile("s_waitcnt vmcnt(0)" : "+v"(A), "+v"(B) :: "memory");
  __builtin_amdgcn_sched_barrier(0);
}

__global__ __launch_bounds__(1024) void crf_init(const float* __restrict__ emit,
                                                 const float* __restrict__ strans,
                                                 const float* __restrict__ etrans) {
  int tid = threadIdx.x;
  g_fbuf[tid] = pack_tag(0u, strans[tid] + emit[tid]);
  g_bbuf[tid] = pack_tag(0u, etrans[tid] + emit[(T_LEN - 1) * NT + tid]);
}

__global__ __launch_bounds__(1024) void crf_score(const float* __restrict__ emit,
                                                  const int* __restrict__ y,
                                                  const float* __restrict__ trans,
                                                  const float* __restrict__ strans,
                                                  const float* __restrict__ etrans,
                                                  float* __restrict__ ws) {
  int tid = threadIdx.x;
  float local = 0.f;
  for (int t = tid; t < T_LEN; t += 1024) {
    int yt = y[t];
    local += emit[t * NT + yt];
    if (t > 0) local += trans[y[t - 1] * NT + yt];
  }
  if (tid == 0) local += strans[y[0]];
  if (tid == 1023) local += etrans[y[T_LEN - 1]];
#pragma unroll
  for (int o = 32; o; o >>= 1) local += __shfl_xor(local, o);
  __shared__ float sm[16];
  if ((tid & 63) == 0) sm[tid >> 6] = local;
  __syncthreads();
  if (tid == 0) {
    float s = 0.f;
    for (int i = 0; i < 16; ++i) s += sm[i];
    ws[4096] = s;
  }
}

// Blocks [0,64): forward chain. Blocks [64,128): backward chain.
// R5 structure (CPB=16, batched serial poll, single coalesced 128B store) plus:
//  (a) cross-step EARLY poll issue: first poll round for step n+1 issued right
//      after step n's store (bIn(n+1)==bOut(n)), overlapping the M-reduce and
//      loop overhead — when producers were already visible, a full serial
//      poll round (~1 MALL RT) is skipped;
//  (b) no fill->GEMV barrier — wave w fills and reads exactly aS[256w,256w+256)
//      (wave-private RAW; per-wave in-order LDS pipe);
//  (c) 2-accumulator GEMV chains.
__global__ __launch_bounds__(NTHR, 1) void crf_scan(const float* __restrict__ emit,
                                                    const float* __restrict__ trans) {
  const int tid = threadIdx.x;
  const bool fwd = blockIdx.x < NBLK;
  const int blk = fwd ? blockIdx.x : (blockIdx.x - NBLK);

  const int c = tid & 15;        // local column (fwd) / row (bwd)
  const int chunk = tid >> 4;    // reduction-dim chunk 0..15 (64 each)
  const int col = blk * CPB + c;
  const int wv = tid >> 6;       // wave 0..3

  u64* buf0 = fwd ? g_fbuf : g_bbuf;
  u64* buf1 = buf0 + NT;
  const int STEPS = fwd ? MID : (T_LEN - 1 - MID);   // 8191 / 8192

  // P fragment: fwd: p = exp(trans[j, col]); bwd: p = exp(trans[col, j]).
  // 8*chunk stagger keeps the 4 distinct LDS lines per wave-read on disjoint
  // bank quads -> conflict-free broadcast reads (unchanged).
  float p[64];
  const int jbase = chunk * 64;
#pragma unroll
  for (int i = 0; i < 16; ++i) {
    int off = (4 * i + 8 * chunk) & 63;
#pragma unroll
    for (int x = 0; x < 4; ++x) {
      int jj = jbase + off + x;
      float tv = fwd ? trans[jj * NT + col] : trans[col * NT + jj];
      p[4 * i + x] = __expf(tv);
    }
  }

  __shared__ __align__(16) float aS[NT];
  __shared__ float partS[64];    // [wave][16 cols]

  // initial block-local scale M = max over this block's 16 seed values
  float M;
  {
    u64 wd = ld_tag(buf0 + col);
    float v = __uint_as_float((u32)wd);
#pragma unroll
    for (int o = 8; o; o >>= 1) v = fmaxf(v, __shfl_xor(v, o));
    M = v;
  }

  // Persistent poll pair + prologue issue for step 1 (bIn = buf0).
  u32x4 A, B;
  ld8_issue(buf0 + (tid << 2), A, B);

  for (int n = 1; n <= STEPS; ++n) {
    u64* bIn  = (n & 1) ? buf0 : buf1;   // holds tag n-1
    u64* bOut = (n & 1) ? buf1 : buf0;   // receives tag n

    const int te = fwd ? n : (T_LEN - 1 - n);
    float e = emit[te * NT + col];       // in flight; drained by the poll wait

    // Serial poll, check-first: the early-issued round is usually already
    // (nearly) landed. Stale self-span reads show tag n-2 -> re-poll (safe).
    const u32 want = (u32)(n - 1);
    const u64* q = bIn + (tid << 2);
    for (;;) {
      vm_wait0p(A, B);
      if (!((A.y ^ want) | (A.w ^ want) | (B.y ^ want) | (B.w ^ want))) break;
      ld8_issue(q, A, B);
    }
    float4 av;
    av.x = __expf(__uint_as_float(A.x) - M);
    av.y = __expf(__uint_as_float(A.z) - M);
    av.z = __expf(__uint_as_float(B.x) - M);
    av.w = __expf(__uint_as_float(B.z) - M);
    ((float4*)aS)[tid] = av;             // one contiguous ds_write_b128

    // NO barrier: wave w wrote aS[256w..256w+256) and reads only that range.

    // GEMV: thread owns (c, chunk): 16 broadcast float4 reads, 2 acc chains
    float s0 = 0.f, s1 = 0.f;
    const float4* aV = (const float4*)aS;
#pragma unroll
    for (int i = 0; i < 16; i += 2) {
      int offA = (4 * i + 8 * chunk) & 63;
      int offB = (4 * i + 4 + 8 * chunk) & 63;
      float4 a4 = aV[(jbase + offA) >> 2];
      float4 b4 = aV[(jbase + offB) >> 2];
      s0 = fmaf(a4.x, p[4 * i + 0], s0);
      s0 = fmaf(a4.y, p[4 * i + 1], s0);
      s0 = fmaf(a4.z, p[4 * i + 2], s0);
      s0 = fmaf(a4.w, p[4 * i + 3], s0);
      s1 = fmaf(b4.x, p[4 * i + 4], s1);
      s1 = fmaf(b4.y, p[4 * i + 5], s1);
      s1 = fmaf(b4.z, p[4 * i + 6], s1);
      s1 = fmaf(b4.w, p[4 * i + 7], s1);
    }
    float s = s0 + s1;
    // reduce over the wave's 4 chunks (tid bits 4,5)
    s += __shfl_xor(s, 16);
    s += __shfl_xor(s, 32);
    if ((tid & 63) < 16) partS[wv * 16 + c] = s;
    __syncthreads();                     // the one cross-wave sync per step

    // final cross-wave combine, done redundantly by every thread (4 LDS reads)
    float tot = partS[c] + partS[16 + c] + partS[32 + c] + partS[48 + c];
    float anew = e + M + __logf(tot);
    // single coalesced 128B store from one wave (do not fragment — R4 lesson)
    if (tid < 16) st_tag(bOut + col, pack_tag((u32)n, anew));

    // EARLY ISSUE for step n+1 (bIn(n+1) == bOut(n)): overlaps the M-reduce
    // and loop overhead with the MALL round trip. Harmless at n == STEPS.
    ld8_issue(bOut + (tid << 2), A, B);

    // block-local M for next step: max over this block's 16 fresh values
    float m2 = anew;
#pragma unroll
    for (int o = 8; o; o >>= 1) m2 = fmaxf(m2, __shfl_xor(m2, o));
    M = m2;
  }
}

__global__ __launch_bounds__(1024) void crf_final(const float* __restrict__ emit,
                                                  const float* __restrict__ ws,
                                                  float* __restrict__ out) {
  int tid = threadIdx.x;
  // alpha_MID: tag 8191 (odd) -> g_fbuf odd half.
  // beta-stream tag 8192 (even) -> g_bbuf even half; stored = beta_MID + emit[MID,:].
  float fa = __uint_as_float((u32)g_fbuf[NT + tid]);
  float bb = __uint_as_float((u32)g_bbuf[tid]);
  float v = fa + bb - emit[MID * NT + tid];   // alpha_MID + beta_MID
  float m = v;
#pragma unroll
  for (int o = 32; o; o >>= 1) m = fmaxf(m, __shfl_xor(m, o));
  __shared__ float sm[16];
  __shared__ float sM;
  if ((tid & 63) == 0) sm[tid >> 6] = m;
  __syncthreads();
  if (tid == 0) {
    float mm = sm[0];
    for (int i = 1; i < 16; ++i) mm = fmaxf(mm, sm[i]);
    sM = mm;
  }
  __syncthreads();
  float Mv = sM;
  float s = __expf(v - Mv);
#pragma unroll
  for (int o = 32; o; o >>= 1) s += __shfl_xor(s, o);
  __shared__ float ss[16];
  if ((tid & 63) == 0) ss[tid >> 6] = s;
  __syncthreads();
  if (tid == 0) {
    float tot = 0.f;
    for (int i = 0; i < 16; ++i) tot += ss[i];
    float logZ = Mv + __logf(tot);
    out[0] = logZ - ws[4096];
  }
}

extern "C" void kernel_launch(void* const* d_in, const int* in_sizes, int n_in,
                              void* d_out, int out_size, void* d_ws, size_t ws_size,
                              hipStream_t stream) {
  const float* emit = (const float*)d_in[0];
  const int* y = (const int*)d_in[1];
  const float* trans = (const float*)d_in[2];
  const float* strans = (const float*)d_in[3];
  const float* etrans = (const float*)d_in[4];
  float* ws = (float*)d_ws;
  float* out = (float*)d_out;

  crf_init<<<1, 1024, 0, stream>>>(emit, strans, etrans);
  crf_score<<<1, 1024, 0, stream>>>(emit, y, trans, strans, etrans, ws);
  crf_scan<<<2 * NBLK, NTHR, 0, stream>>>(emit, trans);
  crf_final<<<1, 1024, 0, stream>>>(emit, ws, out);
}

// Round 9
// 12689.855 us; speedup vs baseline: 1.2242x; 1.2242x over previous
//
#include <hip/hip_runtime.h>

#define T_LEN 16384
#define NT 1024
#define NBLK 64      // blocks per direction (x2 directions)
#define CPB 16       // columns (fwd) / rows (bwd) per block
#define NTHR 256     // 4 waves
#define MID 8191     // fwd computes alpha_MID (8191 steps); bwd beta_MID (8192 steps)

typedef unsigned long long u64;
typedef unsigned int u32;
typedef __attribute__((ext_vector_type(4))) u32 u32x4;

// Exchange buffers (proven protocol): [0..NT) even-parity tags, [NT..2NT) odd.
// tagged word = (step_tag << 32) | float_bits; tag+data fused => no fences needed.
__device__ __align__(32) u64 g_fbuf[2 * NT];
__device__ __align__(32) u64 g_bbuf[2 * NT];

__device__ __forceinline__ u64 pack_tag(u32 tag, float v) {
  return ((u64)tag << 32) | (u64)__float_as_uint(v);
}
__device__ __forceinline__ u64 ld_tag(const u64* p) {
  return __hip_atomic_load(p, __ATOMIC_RELAXED, __HIP_MEMORY_SCOPE_AGENT);
}
__device__ __forceinline__ void st_tag(u64* p, u64 v) {
  __hip_atomic_store(p, v, __ATOMIC_RELAXED, __HIP_MEMORY_SCOPE_AGENT);
}

// Serial fused poll round (the R5-proven shape): 4 contiguous tagged words
// (32B) as 2 dwordx4 + vmcnt(0). sc0+sc1 => coherent at MALL. Do NOT pipeline
// or early-issue this (R7/R8 both regressed).
__device__ __forceinline__ void ld8_dev(const u64* q, u32x4& A, u32x4& B) {
  asm volatile("global_load_dwordx4 %0, %2, off sc0 sc1\n\t"
               "global_load_dwordx4 %1, %2, off offset:16 sc0 sc1\n\t"
               "s_waitcnt vmcnt(0)"
               : "=&v"(A), "=&v"(B)
               : "v"(q)
               : "memory");
}

__global__ __launch_bounds__(1024) void crf_init(const float* __restrict__ emit,
                                                 const float* __restrict__ strans,
                                                 const float* __restrict__ etrans) {
  int tid = threadIdx.x;
  g_fbuf[tid] = pack_tag(0u, strans[tid] + emit[tid]);
  g_bbuf[tid] = pack_tag(0u, etrans[tid] + emit[(T_LEN - 1) * NT + tid]);
}

__global__ __launch_bounds__(1024) void crf_score(const float* __restrict__ emit,
                                                  const int* __restrict__ y,
                                                  const float* __restrict__ trans,
                                                  const float* __restrict__ strans,
                                                  const float* __restrict__ etrans,
                                                  float* __restrict__ ws) {
  int tid = threadIdx.x;
  float local = 0.f;
  for (int t = tid; t < T_LEN; t += 1024) {
    int yt = y[t];
    local += emit[t * NT + yt];
    if (t > 0) local += trans[y[t - 1] * NT + yt];
  }
  if (tid == 0) local += strans[y[0]];
  if (tid == 1023) local += etrans[y[T_LEN - 1]];
#pragma unroll
  for (int o = 32; o; o >>= 1) local += __shfl_xor(local, o);
  __shared__ float sm[16];
  if ((tid & 63) == 0) sm[tid >> 6] = local;
  __syncthreads();
  if (tid == 0) {
    float s = 0.f;
    for (int i = 0; i < 16; ++i) s += sm[i];
    ws[4096] = s;
  }
}

// Blocks [0,64): forward chain. Blocks [64,128): backward chain.
// Exact R5 (12.66ms) structure: batched serial poll, barrier-2, combine,
// single coalesced 128B store. Two isolated deltas vs R5:
//  (b) no fill->GEMV barrier — wave w writes aS[256w..256w+256) via
//      ((float4*)aS)[tid] and its GEMV (chunk=tid>>4) reads exactly that
//      range: wave-private RAW on the in-order per-wave LDS pipe. Early
//      waves start their GEMV while slow waves still poll.
//  (c) 2-accumulator GEMV chains (halved FMA dep chain).
__global__ __launch_bounds__(NTHR, 1) void crf_scan(const float* __restrict__ emit,
                                                    const float* __restrict__ trans) {
  const int tid = threadIdx.x;
  const bool fwd = blockIdx.x < NBLK;
  const int blk = fwd ? blockIdx.x : (blockIdx.x - NBLK);

  const int c = tid & 15;        // local column (fwd) / row (bwd)
  const int chunk = tid >> 4;    // reduction-dim chunk 0..15 (64 each)
  const int col = blk * CPB + c;
  const int wv = tid >> 6;       // wave 0..3

  u64* buf0 = fwd ? g_fbuf : g_bbuf;
  u64* buf1 = buf0 + NT;
  const int STEPS = fwd ? MID : (T_LEN - 1 - MID);   // 8191 / 8192

  // P fragment: fwd: p = exp(trans[j, col]); bwd: p = exp(trans[col, j]).
  // 8*chunk stagger keeps the 4 distinct LDS lines per wave-read on disjoint
  // bank quads -> conflict-free broadcast reads (unchanged).
  float p[64];
  const int jbase = chunk * 64;
#pragma unroll
  for (int i = 0; i < 16; ++i) {
    int off = (4 * i + 8 * chunk) & 63;
#pragma unroll
    for (int x = 0; x < 4; ++x) {
      int jj = jbase + off + x;
      float tv = fwd ? trans[jj * NT + col] : trans[col * NT + jj];
      p[4 * i + x] = __expf(tv);
    }
  }

  __shared__ __align__(16) float aS[NT];
  __shared__ float partS[64];    // [wave][16 cols]

  // initial block-local scale M = max over this block's 16 seed values
  float M;
  {
    u64 wd = ld_tag(buf0 + col);
    float v = __uint_as_float((u32)wd);
#pragma unroll
    for (int o = 8; o; o >>= 1) v = fmaxf(v, __shfl_xor(v, o));
    M = v;
  }

  for (int n = 1; n <= STEPS; ++n) {
    u64* bIn  = (n & 1) ? buf0 : buf1;   // holds tag n-1
    u64* bOut = (n & 1) ? buf1 : buf0;   // receives tag n

    const int te = fwd ? n : (T_LEN - 1 - n);
    float e = emit[te * NT + col];       // issued before the poll; overlaps it

    // Batched serial poll on [4*tid, 4*tid+4) — one producer per thread.
    const u32 want = (u32)(n - 1);
    const u64* q = bIn + (tid << 2);
    u32x4 A, B;
    for (;;) {
      ld8_dev(q, A, B);
      if (!((A.y ^ want) | (A.w ^ want) | (B.y ^ want) | (B.w ^ want))) break;
    }
    float4 av;
    av.x = __expf(__uint_as_float(A.x) - M);
    av.y = __expf(__uint_as_float(A.z) - M);
    av.z = __expf(__uint_as_float(B.x) - M);
    av.w = __expf(__uint_as_float(B.z) - M);
    ((float4*)aS)[tid] = av;             // one contiguous ds_write_b128

    // NO barrier here: wave-private RAW (see kernel comment).

    // GEMV: thread owns (c, chunk): 16 broadcast float4 reads, 2 acc chains
    float s0 = 0.f, s1 = 0.f;
    const float4* aV = (const float4*)aS;
#pragma unroll
    for (int i = 0; i < 16; i += 2) {
      int offA = (4 * i + 8 * chunk) & 63;
      int offB = (4 * i + 4 + 8 * chunk) & 63;
      float4 a4 = aV[(jbase + offA) >> 2];
      float4 b4 = aV[(jbase + offB) >> 2];
      s0 = fmaf(a4.x, p[4 * i + 0], s0);
      s0 = fmaf(a4.y, p[4 * i + 1], s0);
      s0 = fmaf(a4.z, p[4 * i + 2], s0);
      s0 = fmaf(a4.w, p[4 * i + 3], s0);
      s1 = fmaf(b4.x, p[4 * i + 4], s1);
      s1 = fmaf(b4.y, p[4 * i + 5], s1);
      s1 = fmaf(b4.z, p[4 * i + 6], s1);
      s1 = fmaf(b4.w, p[4 * i + 7], s1);
    }
    float s = s0 + s1;
    // reduce over the wave's 4 chunks (tid bits 4,5)
    s += __shfl_xor(s, 16);
    s += __shfl_xor(s, 32);
    if ((tid & 63) < 16) partS[wv * 16 + c] = s;
    __syncthreads();                     // the one cross-wave sync per step

    // final cross-wave combine, done redundantly by every thread (4 LDS reads)
    float tot = partS[c] + partS[16 + c] + partS[32 + c] + partS[48 + c];
    float anew = e + M + __logf(tot);
    // single coalesced 128B store from one wave (do not fragment — R4 lesson)
    if (tid < 16) st_tag(bOut + col, pack_tag((u32)n, anew));

    // block-local M for next step: max over this block's 16 fresh values
    float m2 = anew;
#pragma unroll
    for (int o = 8; o; o >>= 1) m2 = fmaxf(m2, __shfl_xor(m2, o));
    M = m2;
  }
}

__global__ __launch_bounds__(1024) void crf_final(const float* __restrict__ emit,
                                                  const float* __restrict__ ws,
                                                  float* __restrict__ out) {
  int tid = threadIdx.x;
  // alpha_MID: tag 8191 (odd) -> g_fbuf odd half.
  // beta-stream tag 8192 (even) -> g_bbuf even half; stored = beta_MID + emit[MID,:].
  float fa = __uint_as_float((u32)g_fbuf[NT + tid]);
  float bb = __uint_as_float((u32)g_bbuf[tid]);
  float v = fa + bb - emit[MID * NT + tid];   // alpha_MID + beta_MID
  float m = v;
#pragma unroll
  for (int o = 32; o; o >>= 1) m = fmaxf(m, __shfl_xor(m, o));
  __shared__ float sm[16];
  __shared__ float sM;
  if ((tid & 63) == 0) sm[tid >> 6] = m;
  __syncthreads();
  if (tid == 0) {
    float mm = sm[0];
    for (int i = 1; i < 16; ++i) mm = fmaxf(mm, sm[i]);
    sM = mm;
  }
  __syncthreads();
  float Mv = sM;
  float s = __expf(v - Mv);
#pragma unroll
  for (int o = 32; o; o >>= 1) s += __shfl_xor(s, o);
  __shared__ float ss[16];
  if ((tid & 63) == 0) ss[tid >> 6] = s;
  __syncthreads();
  if (tid == 0) {
    float tot = 0.f;
    for (int i = 0; i < 16; ++i) tot += ss[i];
    float logZ = Mv + __logf(tot);
    out[0] = logZ - ws[4096];
  }
}

extern "C" void kernel_launch(void* const* d_in, const int* in_sizes, int n_in,
                              void* d_out, int out_size, void* d_ws, size_t ws_size,
                              hipStream_t stream) {
  const float* emit = (const float*)d_in[0];
  const int* y = (const int*)d_in[1];
  const float* trans = (const float*)d_in[2];
  const float* strans = (const float*)d_in[3];
  const float* etrans = (const float*)d_in[4];
  float* ws = (float*)d_ws;
  float* out = (float*)d_out;

  crf_init<<<1, 1024, 0, stream>>>(emit, strans, etrans);
  crf_score<<<1, 1024, 0, stream>>>(emit, y, trans, strans, etrans, ws);
  crf_scan<<<2 * NBLK, NTHR, 0, stream>>>(emit, trans);
  crf_final<<<1, 1024, 0, stream>>>(emit, ws, out);
}